// Round 7
// baseline (1870.523 us; speedup 1.0000x reference)
//
#include <hip/hip_runtime.h>
#include <math.h>

#define BQ 8
#define NQ 2048
#define SQ 1024
#define KQ 64
#define CIN 64
#define H1Q 128
#define COUT 256
#define R2F 0.04f     /* f32(0.2**2 in double) = 0x3D23D70A; NOT 0.2f*0.2f */
#define CAP 512
#define XW_ROWS 8
#define XW_BLOCKS ((BQ*NQ)/XW_ROWS)   /* 2048 */
#define W2C_BLOCKS 64                 /* w2 -> bf16 fragment conversion */

typedef float f32x2 __attribute__((ext_vector_type(2)));
typedef float f32x4v __attribute__((ext_vector_type(4)));
typedef short bf16x8 __attribute__((ext_vector_type(8)));
typedef unsigned int u32;
typedef unsigned short u16;

__device__ __forceinline__ u16 f2bf(float f) {          // RNE f32->bf16
    u32 u = __builtin_bit_cast(u32, f);
    return (u16)((u + 0x7FFFu + ((u >> 16) & 1u)) >> 16);
}

// ---------------------------------------------------------------------------
// DPP wave-max helper. old = -inf so shifted-in lanes contribute identity.
// ---------------------------------------------------------------------------
template <int CTRL>
__device__ __forceinline__ float maxdpp(float x) {
    int xi = __builtin_bit_cast(int, x);
    int yi = __builtin_amdgcn_update_dpp((int)0xFF800000, xi, CTRL, 0xF, 0xF, false);
    return fmaxf(x, __builtin_bit_cast(float, yi));
}

// ---------------------------------------------------------------------------
// Fused dispatch:
//   blocks [0,8)                         : FPS, one wave per cloud
//   blocks [8, 8+XW_BLOCKS)              : xw = x @ w1[:64] + b1
//   blocks [8+XW_BLOCKS, +W2C_BLOCKS)    : w2 f32 -> bf16 MFMA-fragment order
// ---------------------------------------------------------------------------
__global__ __launch_bounds__(64)
void fps_xw_kernel(const float* __restrict__ pos, int* __restrict__ idx_out,
                   float* __restrict__ q_out, float* __restrict__ batch_out,
                   const float* __restrict__ x, const float* __restrict__ w1,
                   const float* __restrict__ b1, float* __restrict__ xw,
                   const float* __restrict__ w2, u16* __restrict__ w2f) {
#pragma clang fp contract(off)
    __shared__ float lnpos[NQ][4];          // NEGATED coords, padded for b128
    __shared__ int   sel[SQ];
    __shared__ float xs[XW_ROWS][CIN];

    const int lane = threadIdx.x;

    if (blockIdx.x >= 8 + XW_BLOCKS) {
        // ---- w2 fragment conversion: one 1KB chunk (w,ct,kt) per block ----
        // conv wave w reads chunk cb = w*16 + ct*4 + kt; lane l gets
        // B[k=kt*32+(l>>4)*8+j][n=w*64+ct*16+(l&15)] as 8 bf16 (16B).
        const int cb = blockIdx.x - (8 + XW_BLOCKS);
        const int w  = cb >> 4, ct = (cb >> 2) & 3, kt = cb & 3;
        const int n  = w*64 + ct*16 + (lane & 15);
        const int k0 = kt*32 + (lane >> 4)*8;
        u32 pk[4];
#pragma unroll
        for (int jp = 0; jp < 4; ++jp) {
            u16 lo = f2bf(w2[(size_t)(k0 + 2*jp    )*COUT + n]);
            u16 hi = f2bf(w2[(size_t)(k0 + 2*jp + 1)*COUT + n]);
            pk[jp] = (u32)lo | ((u32)hi << 16);
        }
        u32* dst = (u32*)(w2f + ((size_t)cb*64 + lane)*8);
        dst[0] = pk[0]; dst[1] = pk[1]; dst[2] = pk[2]; dst[3] = pk[3];
        return;
    }

    if (blockIdx.x >= 8) {
        // ---------------- xw path: 8 rows, 64 threads, 2 h-cols/thread ----
        const int r0 = (blockIdx.x - 8) * XW_ROWS;
        for (int i = lane; i < XW_ROWS*CIN; i += 64)
            xs[i >> 6][i & 63] = x[(size_t)(r0 + (i >> 6))*CIN + (i & 63)];
        __syncthreads();
        const int h0 = lane, h1 = lane + 64;
        float acc0[XW_ROWS], acc1[XW_ROWS];
        float bb0 = b1[h0], bb1 = b1[h1];
#pragma unroll
        for (int r = 0; r < XW_ROWS; ++r) { acc0[r] = bb0; acc1[r] = bb1; }
        for (int c = 0; c < CIN; ++c) {
            float w0 = w1[c*H1Q + h0];
            float w2v = w1[c*H1Q + h1];
#pragma unroll
            for (int r = 0; r < XW_ROWS; ++r) {
                float xv = xs[r][c];
                acc0[r] = fmaf(xv, w0,  acc0[r]);
                acc1[r] = fmaf(xv, w2v, acc1[r]);
            }
        }
#pragma unroll
        for (int r = 0; r < XW_ROWS; ++r) {
            xw[(size_t)(r0 + r)*H1Q + h0] = acc0[r];
            xw[(size_t)(r0 + r)*H1Q + h1] = acc1[r];
        }
        return;
    }

    // ---------------- FPS path (one wave per cloud) ----------------
    const int b = blockIdx.x;
    const float* p = pos + (size_t)b * NQ * 3;

    f32x2 px[16], py[16], pz[16], dist[16];
#pragma unroll
    for (int r = 0; r < 16; ++r) {
        int i0 = lane * 32 + 2 * r;
        float x0 = p[3*i0],   y0 = p[3*i0+1], z0 = p[3*i0+2];
        float x1 = p[3*i0+3], y1 = p[3*i0+4], z1 = p[3*i0+5];
        px[r] = (f32x2){x0, x1}; py[r] = (f32x2){y0, y1}; pz[r] = (f32x2){z0, z1};
        lnpos[i0][0]   = -x0; lnpos[i0][1]   = -y0; lnpos[i0][2]   = -z0; lnpos[i0][3]   = 0.f;
        lnpos[i0+1][0] = -x1; lnpos[i0+1][1] = -y1; lnpos[i0+1][2] = -z1; lnpos[i0+1][3] = 0.f;
    }
    if (lane == 0) sel[0] = 0;
    __syncthreads();

    float cx = p[0], cy = p[1], cz = p[2];

    float lmax;
    {
        f32x2 ncx = (f32x2){-cx, -cx}, ncy = (f32x2){-cy, -cy}, ncz = (f32x2){-cz, -cz};
        lmax = -INFINITY;
#pragma unroll
        for (int r = 0; r < 16; ++r) {
            f32x2 dx = px[r] + ncx, dy = py[r] + ncy, dz = pz[r] + ncz;
            f32x2 a = dx * dx, bb = dy * dy, cc = dz * dz;
            f32x2 s = (a + bb) + cc;
            dist[r] = s;
            lmax = fmaxf(fmaxf(lmax, s.x), s.y);
        }
    }

    for (int s = 1; s < SQ; ++s) {
        // ---- per-lane first slot holding own lmax (overlaps DPP below) ----
        int ra = 1000, rb = 1000;
#pragma unroll
        for (int r = 15; r >= 0; --r) {
            ra = (dist[r].x == lmax) ? 2*r     : ra;
            rb = (dist[r].y == lmax) ? 2*r + 1 : rb;
        }
        int ridx = min(ra, rb);

        // ---- wave max via DPP ----
        float m = lmax;
        m = maxdpp<0x111>(m);
        m = maxdpp<0x112>(m);
        m = maxdpp<0x114>(m);
        m = maxdpp<0x118>(m);
        m = maxdpp<0x142>(m);
        m = maxdpp<0x143>(m);
        float wmax = __builtin_bit_cast(
            float, __builtin_amdgcn_readlane(__builtin_bit_cast(int, m), 63));

        unsigned long long msk = __ballot(lmax == wmax);
        int wl = __ffsll(msk) - 1;
        int rw = __builtin_amdgcn_readlane(ridx, wl);
        int gidx = wl * 32 + rw;
        if (lane == 0) sel[s] = gidx;

        float4 nc4 = *reinterpret_cast<const float4*>(&lnpos[gidx][0]);
        f32x2 ncx = (f32x2){nc4.x, nc4.x};
        f32x2 ncy = (f32x2){nc4.y, nc4.y};
        f32x2 ncz = (f32x2){nc4.z, nc4.z};

        float nm = -INFINITY;
#pragma unroll
        for (int r = 0; r < 16; ++r) {
            f32x2 dx = px[r] + ncx, dy = py[r] + ncy, dz = pz[r] + ncz;
            f32x2 a = dx * dx, bb = dy * dy, cc = dz * dz;
            f32x2 nd = (a + bb) + cc;
            f32x2 v = __builtin_elementwise_min(dist[r], nd);
            dist[r] = v;
            nm = fmaxf(fmaxf(nm, v.x), v.y);
        }
        lmax = nm;
    }
    __syncthreads();

    for (int s = lane; s < SQ; s += 64) {
        int id = sel[s];
        idx_out[b*SQ + s] = id;
        q_out[(size_t)(b*SQ + s)*3 + 0] = -lnpos[id][0];
        q_out[(size_t)(b*SQ + s)*3 + 1] = -lnpos[id][1];
        q_out[(size_t)(b*SQ + s)*3 + 2] = -lnpos[id][2];
        batch_out[b*SQ + s] = (float)b;
    }
}

// ---------------------------------------------------------------------------
// Kernel 2: radius ball query (unchanged).
// ---------------------------------------------------------------------------
__global__ __launch_bounds__(256)
void ball_kernel(const float* __restrict__ pos, const float* __restrict__ q,
                 int* __restrict__ nbr, int* __restrict__ cnt_out) {
    const int cidx = blockIdx.x;
    const int b = cidx >> 10;
    __shared__ float sd2[CAP];
    __shared__ int   sid[CAP];
    __shared__ int   s_cnt, s_w;
    if (threadIdx.x == 0) { s_cnt = 0; s_w = 0; }
    __syncthreads();

    const float qx = q[(size_t)cidx*3], qy = q[(size_t)cidx*3+1], qz = q[(size_t)cidx*3+2];
    const float* p = pos + (size_t)b * NQ * 3;
    for (int i = threadIdx.x; i < NQ; i += 256) {
        float dx = __fsub_rn(qx, p[3*i]);
        float dy = __fsub_rn(qy, p[3*i+1]);
        float dz = __fsub_rn(qz, p[3*i+2]);
        float d2 = __fadd_rn(__fadd_rn(__fmul_rn(dx, dx), __fmul_rn(dy, dy)),
                             __fmul_rn(dz, dz));
        if (d2 <= R2F) {
            int slot = atomicAdd(&s_cnt, 1);
            if (slot < CAP) { sd2[slot] = d2; sid[slot] = i; }
        }
    }
    __syncthreads();
    int cnt = min(s_cnt, CAP);
    if (cnt <= KQ) {
        for (int t = threadIdx.x; t < cnt; t += 256) nbr[(size_t)cidx*KQ + t] = sid[t];
        if (threadIdx.x == 0) cnt_out[cidx] = cnt;
    } else {
        for (int t = threadIdx.x; t < cnt; t += 256) {
            float d = sd2[t]; int id = sid[t];
            int rank = 0;
            for (int u = 0; u < cnt; ++u) {
                float du = sd2[u];
                rank += (du < d || (du == d && sid[u] < id)) ? 1 : 0;
            }
            if (rank < KQ) { int w = atomicAdd(&s_w, 1); nbr[(size_t)cidx*KQ + w] = id; }
        }
        if (threadIdx.x == 0) cnt_out[cidx] = KQ;
    }
}

// ---------------------------------------------------------------------------
// Kernel 3: conv via bf16 MFMA.
// Phase A: h1 -> bf16 into XOR-swizzled LDS (row e, byte ^= (e&7)<<4).
// Phase B: 4 waves; wave w owns cols [w*64,(w+1)*64): 4mt x 4ct x 4kt
//          mfma_f32_16x16x32_bf16; A from LDS, B from fragment-ordered w2f.
// Epilogue: mask rows>=cnt to -inf, max over rows in-reg + shfl_xor(16,32).
// ---------------------------------------------------------------------------
__global__ __launch_bounds__(256)
void conv_kernel(const float* __restrict__ pos, const float* __restrict__ q,
                 const int* __restrict__ nbr, const int* __restrict__ cnt_in,
                 const float* __restrict__ xw, const float* __restrict__ w1,
                 const u16* __restrict__ w2f, const float* __restrict__ b2,
                 float* __restrict__ out) {
    const int cidx = blockIdx.x;
    const int b = cidx >> 10;
    const int tid = threadIdx.x;
    __shared__ u16  hs[KQ * H1Q];           // 16 KB, swizzled bf16
    __shared__ float dxs[KQ], dys[KQ], dzs[KQ];
    __shared__ int   js[KQ];

    const int cnt = cnt_in[cidx];
    if (cnt == 0) {
        out[(size_t)cidx*COUT + tid] = 0.0f;
        return;
    }
    const float qx = q[(size_t)cidx*3], qy = q[(size_t)cidx*3+1], qz = q[(size_t)cidx*3+2];
    const float* p = pos + (size_t)b * NQ * 3;
    if (tid < cnt) {
        int j = nbr[(size_t)cidx*KQ + tid];
        js[tid]  = j;
        dxs[tid] = p[3*j]   - qx;
        dys[tid] = p[3*j+1] - qy;
        dzs[tid] = p[3*j+2] - qz;
    }
    __syncthreads();

    const float* w1p = w1 + (size_t)CIN * H1Q;   // rows 64..66
    for (int f2 = tid; f2 < KQ*(H1Q/2); f2 += 256) {
        int e = f2 >> 6, hp = (f2 & 63) * 2;
        u32 pack;
        if (e < cnt) {
            int j = js[e];
            const f32x2 xv = *(const f32x2*)(xw + ((size_t)b*NQ + j)*H1Q + hp);
            float dx = dxs[e], dy = dys[e], dz = dzs[e];
            float v0 = xv.x, v1 = xv.y;
            v0 = fmaf(dx, w1p[hp],       v0);
            v0 = fmaf(dy, w1p[H1Q+hp],   v0);
            v0 = fmaf(dz, w1p[2*H1Q+hp], v0);
            v1 = fmaf(dx, w1p[hp+1],       v1);
            v1 = fmaf(dy, w1p[H1Q+hp+1],   v1);
            v1 = fmaf(dz, w1p[2*H1Q+hp+1], v1);
            v0 = fmaxf(v0, 0.0f); v1 = fmaxf(v1, 0.0f);
            pack = (u32)f2bf(v0) | ((u32)f2bf(v1) << 16);
        } else {
            pack = 0u;   // zero rows >= cnt (masked at epilogue anyway)
        }
        u32 byte = (u32)e*256 + (((u32)hp*2) ^ (((u32)e & 7) << 4));
        *(u32*)((char*)hs + byte) = pack;
    }
    __syncthreads();

    const int w    = tid >> 6;       // wave -> col slice
    const int lane = tid & 63;
    const int row  = lane & 15;      // M row within tile / N col for B
    const int lg   = lane >> 4;      // k sub-group

    f32x4v acc[16];
#pragma unroll
    for (int i = 0; i < 16; ++i) acc[i] = (f32x4v){0.f, 0.f, 0.f, 0.f};

#pragma unroll
    for (int kt = 0; kt < 4; ++kt) {
        bf16x8 a[4];
#pragma unroll
        for (int mt = 0; mt < 4; ++mt) {
            u32 byte = (u32)(mt*16 + row)*256
                     + (((u32)(kt*64 + lg*16)) ^ (((u32)row & 7) << 4));
            a[mt] = *(const bf16x8*)((const char*)hs + byte);
        }
#pragma unroll
        for (int ct = 0; ct < 4; ++ct) {
            const int chunk = (w*4 + ct)*4 + kt;
            bf16x8 bf = *(const bf16x8*)(w2f + ((size_t)chunk*64 + lane)*8);
#pragma unroll
            for (int mt = 0; mt < 4; ++mt)
                acc[ct*4 + mt] = __builtin_amdgcn_mfma_f32_16x16x32_bf16(
                    a[mt], bf, acc[ct*4 + mt], 0, 0, 0);
        }
    }

#pragma unroll
    for (int ct = 0; ct < 4; ++ct) {
        float v = -INFINITY;
#pragma unroll
        for (int mt = 0; mt < 4; ++mt) {
#pragma unroll
            for (int r = 0; r < 4; ++r) {
                int rrow = mt*16 + lg*4 + r;          // edge index
                float av = acc[ct*4 + mt][r];
                v = fmaxf(v, rrow < cnt ? av : -INFINITY);
            }
        }
        v = fmaxf(v, __shfl_xor(v, 16));
        v = fmaxf(v, __shfl_xor(v, 32));
        int n = w*64 + ct*16 + row;
        if (lg == 0) out[(size_t)cidx*COUT + n] = v + b2[n];
    }
}

// ---------------------------------------------------------------------------
// Calibration: spin until s_memtime advances 2.4M ticks. dur_us of this
// dispatch reads out the effective shader clock (1000us -> 2.4GHz;
// 2400us -> 1.0GHz). Removed next round.
// ---------------------------------------------------------------------------
__global__ __launch_bounds__(64)
void calib_kernel(int* __restrict__ sink) {
#if __has_builtin(__builtin_amdgcn_s_memtime)
    if (threadIdx.x == 0) {
        unsigned long long t0 = __builtin_amdgcn_s_memtime();
        unsigned long long t;
        do { t = __builtin_amdgcn_s_memtime(); } while (t - t0 < 2400000ULL);
        if (t == 0xFFFFFFFFFFFFFFFFULL) sink[0] = 1;   // never true; keeps loop
    }
#endif
}

// ---------------------------------------------------------------------------
extern "C" void kernel_launch(void* const* d_in, const int* in_sizes, int n_in,
                              void* d_out, int out_size, void* d_ws, size_t ws_size,
                              hipStream_t stream) {
    const float* x   = (const float*)d_in[0];
    const float* pos = (const float*)d_in[1];
    const float* w1  = (const float*)d_in[3];
    const float* b1  = (const float*)d_in[4];
    const float* w2  = (const float*)d_in[5];
    const float* b2  = (const float*)d_in[6];

    float* out  = (float*)d_out;                         // [B*S, 256]
    float* qbuf = out + (size_t)BQ*SQ*COUT;              // [B*S, 3]
    float* bbuf = qbuf + (size_t)BQ*SQ*3;                // [B*S]

    char* ws = (char*)d_ws;
    int*   idx = (int*)(ws);                                     // 32 KB
    int*   cnt = (int*)(ws + 32768);                             // 32 KB
    int*   nbr = (int*)(ws + 65536);                             // 2 MB
    float* xw  = (float*)(ws + 65536 + (size_t)BQ*SQ*KQ*4);      // 8 MB
    u16*   w2f = (u16*)(ws + 65536 + (size_t)BQ*SQ*KQ*4
                            + (size_t)BQ*NQ*H1Q*4);              // 64 KB

    const int grid = 8 + XW_BLOCKS + W2C_BLOCKS;
    fps_xw_kernel<<<grid, 64, 0, stream>>>(pos, idx, qbuf, bbuf,
                                           x, w1, b1, xw, w2, w2f);
    ball_kernel  <<<BQ*SQ, 256, 0, stream>>>(pos, qbuf, nbr, cnt);
    conv_kernel  <<<BQ*SQ, 256, 0, stream>>>(pos, qbuf, nbr, cnt, xw, w1,
                                             w2f, b2, out);
    calib_kernel <<<1, 64, 0, stream>>>(idx);
}

// Round 8
// 621.937 us; speedup vs baseline: 3.0076x; 3.0076x over previous
//
#include <hip/hip_runtime.h>
#include <math.h>

#define BQ 8
#define NQ 2048
#define SQ 1024
#define KQ 64
#define CIN 64
#define H1Q 128
#define COUT 256
#define R2F 0.04f     /* f32(0.2**2 in double) = 0x3D23D70A; NOT 0.2f*0.2f */
#define CAP 512
#define XW_ROWS 16
#define XW_BLOCKS ((BQ*NQ)/XW_ROWS)   /* 1024 */
#define W2C_BLOCKS 16                 /* 16 blocks x 4 chunks = 64 chunks */

typedef float f32x2 __attribute__((ext_vector_type(2)));
typedef float f32x4v __attribute__((ext_vector_type(4)));
typedef short bf16x8 __attribute__((ext_vector_type(8)));
typedef unsigned int u32;
typedef unsigned short u16;

__device__ __forceinline__ u16 f2bf(float f) {          // RNE f32->bf16
    u32 u = __builtin_bit_cast(u32, f);
    return (u16)((u + 0x7FFFu + ((u >> 16) & 1u)) >> 16);
}

template <int CTRL>
__device__ __forceinline__ float maxdpp(float x) {
    int xi = __builtin_bit_cast(int, x);
    int yi = __builtin_amdgcn_update_dpp((int)0xFF800000, xi, CTRL, 0xF, 0xF, false);
    return fmaxf(x, __builtin_bit_cast(float, yi));
}

// ---------------------------------------------------------------------------
// Fused dispatch (256-thread blocks):
//   blocks [0,8)                       : FPS, FOUR waves per cloud
//   blocks [8, 8+XW_BLOCKS)            : xw = x @ w1[:64] + b1
//   blocks [8+XW_BLOCKS, +W2C_BLOCKS)  : w2 f32 -> bf16 MFMA-fragment order
//
// FPS: 8 points/lane as 4 x f32x2; gidx = tid*8 + r so (wave,lane,reg,elem)
// lexicographic == index order (first-occurrence argmax preserved).
// Per iteration: per-wave update+DPP argmax in parallel on 4 SIMDs; lane 0
// of each wave publishes (dist_bits, idx) to parity-buffered LDS; ONE
// __syncthreads(); every lane picks the best of 4 candidates (u32 compare,
// valid since d2 >= 0; tie -> smaller idx); uniform ds_read_b128 of the
// NEGATED center. d2 bit-exact: ((dx*dx+dy*dy)+dz*dz), no FMA; x+(-c)==x-c.
// ---------------------------------------------------------------------------
__global__ __launch_bounds__(256)
void fps_xw_kernel(const float* __restrict__ pos, int* __restrict__ idx_out,
                   float* __restrict__ q_out, float* __restrict__ batch_out,
                   const float* __restrict__ x, const float* __restrict__ w1,
                   const float* __restrict__ b1, float* __restrict__ xw,
                   const float* __restrict__ w2, u16* __restrict__ w2f) {
#pragma clang fp contract(off)
    __shared__ float lnpos[NQ][4];              // NEGATED coords, b128-padded
    __shared__ int   sel[SQ];
    __shared__ alignas(16) u32 red[2][8];       // [parity][wave*2 + {val,idx}]

    const int tid = threadIdx.x;

    if (blockIdx.x >= 8 + XW_BLOCKS) {
        // ---- w2 fragment conversion: chunk (w,ct,kt); lane l gets
        // B[k=kt*32+(l>>4)*8+j][n=w*64+ct*16+(l&15)] as 8 bf16 (16B). ----
        const int cb   = (blockIdx.x - (8 + XW_BLOCKS)) * 4 + (tid >> 6);
        const int lane = tid & 63;
        const int w  = cb >> 4, ct = (cb >> 2) & 3, kt = cb & 3;
        const int n  = w*64 + ct*16 + (lane & 15);
        const int k0 = kt*32 + (lane >> 4)*8;
        u32 pk[4];
#pragma unroll
        for (int jp = 0; jp < 4; ++jp) {
            u16 lo = f2bf(w2[(size_t)(k0 + 2*jp    )*COUT + n]);
            u16 hi = f2bf(w2[(size_t)(k0 + 2*jp + 1)*COUT + n]);
            pk[jp] = (u32)lo | ((u32)hi << 16);
        }
        u32* dst = (u32*)(w2f + ((size_t)cb*64 + lane)*8);
        dst[0] = pk[0]; dst[1] = pk[1]; dst[2] = pk[2]; dst[3] = pk[3];
        return;
    }

    if (blockIdx.x >= 8) {
        // ---- xw path: 16 rows/block; h = tid&127, row-half = tid>>7 ----
        __shared__ float xs[XW_ROWS][CIN];
        const int r0 = (blockIdx.x - 8) * XW_ROWS;
        for (int i = tid; i < XW_ROWS*CIN; i += 256)
            xs[i >> 6][i & 63] = x[(size_t)(r0 + (i >> 6))*CIN + (i & 63)];
        __syncthreads();
        const int h = tid & 127, rbase = (tid >> 7) * 8;
        float acc[8];
        float bb = b1[h];
#pragma unroll
        for (int r = 0; r < 8; ++r) acc[r] = bb;
        for (int c = 0; c < CIN; ++c) {
            float wv = w1[c*H1Q + h];
#pragma unroll
            for (int r = 0; r < 8; ++r)
                acc[r] = fmaf(xs[rbase + r][c], wv, acc[r]);
        }
#pragma unroll
        for (int r = 0; r < 8; ++r)
            xw[(size_t)(r0 + rbase + r)*H1Q + h] = acc[r];
        return;
    }

    // ---------------- FPS path: 4 waves per cloud ----------------
    const int b = blockIdx.x;
    const int lane = tid & 63, wid = tid >> 6;
    const float* p = pos + (size_t)b * NQ * 3;

    f32x2 px[4], py[4], pz[4], dist[4];
#pragma unroll
    for (int r = 0; r < 4; ++r) {
        int i0 = tid * 8 + 2 * r;
        float x0 = p[3*i0],   y0 = p[3*i0+1], z0 = p[3*i0+2];
        float x1 = p[3*i0+3], y1 = p[3*i0+4], z1 = p[3*i0+5];
        px[r] = (f32x2){x0, x1}; py[r] = (f32x2){y0, y1}; pz[r] = (f32x2){z0, z1};
        lnpos[i0][0]   = -x0; lnpos[i0][1]   = -y0; lnpos[i0][2]   = -z0; lnpos[i0][3]   = 0.f;
        lnpos[i0+1][0] = -x1; lnpos[i0+1][1] = -y1; lnpos[i0+1][2] = -z1; lnpos[i0+1][3] = 0.f;
    }
    if (tid == 0) sel[0] = 0;
    __syncthreads();

    float cx = p[0], cy = p[1], cz = p[2];
    float lmax;
    {
        f32x2 ncx = (f32x2){-cx, -cx}, ncy = (f32x2){-cy, -cy}, ncz = (f32x2){-cz, -cz};
        lmax = -INFINITY;
#pragma unroll
        for (int r = 0; r < 4; ++r) {
            f32x2 dx = px[r] + ncx, dy = py[r] + ncy, dz = pz[r] + ncz;
            f32x2 a = dx * dx, bb = dy * dy, cc = dz * dz;
            f32x2 s = (a + bb) + cc;
            dist[r] = s;
            lmax = fmaxf(fmaxf(lmax, s.x), s.y);
        }
    }

    for (int s = 1; s < SQ; ++s) {
        const int par = s & 1;

        // ---- per-lane first slot holding lmax (4-deep chains) ----
        int ra = 1000, rb = 1000;
#pragma unroll
        for (int r = 3; r >= 0; --r) {
            ra = (dist[r].x == lmax) ? 2*r     : ra;
            rb = (dist[r].y == lmax) ? 2*r + 1 : rb;
        }
        int ridx = min(ra, rb);

        // ---- per-wave DPP max (parallel across the 4 SIMDs) ----
        float m = lmax;
        m = maxdpp<0x111>(m);
        m = maxdpp<0x112>(m);
        m = maxdpp<0x114>(m);
        m = maxdpp<0x118>(m);
        m = maxdpp<0x142>(m);
        m = maxdpp<0x143>(m);
        float wmax = __builtin_bit_cast(
            float, __builtin_amdgcn_readlane(__builtin_bit_cast(int, m), 63));

        unsigned long long msk = __ballot(lmax == wmax);
        int wl = __ffsll(msk) - 1;
        int rw = __builtin_amdgcn_readlane(ridx, wl);
        u32 widx = (u32)((wl << 3) + rw + (wid << 9));  // global index

        if (lane == 0) {
            red[par][wid*2    ] = __builtin_bit_cast(u32, wmax);
            red[par][wid*2 + 1] = widx;
        }
        __syncthreads();   // ONE barrier/iter; parity buffer avoids WAR race

        // ---- all lanes: best of 4 (u32 compare ok: d2>=0; tie->min idx) ----
        uint4 c01 = *(const uint4*)&red[par][0];
        uint4 c23 = *(const uint4*)&red[par][4];
        u32 bv = c01.x, bi = c01.y;
        if (c01.z > bv || (c01.z == bv && c01.w < bi)) { bv = c01.z; bi = c01.w; }
        if (c23.x > bv || (c23.x == bv && c23.y < bi)) { bv = c23.x; bi = c23.y; }
        if (c23.z > bv || (c23.z == bv && c23.w < bi)) { bv = c23.z; bi = c23.w; }
        if (tid == 0) sel[s] = (int)bi;

        // ---- uniform ds_read_b128 of NEGATED center ----
        float4 nc4 = *reinterpret_cast<const float4*>(&lnpos[bi][0]);
        f32x2 ncx = (f32x2){nc4.x, nc4.x};
        f32x2 ncy = (f32x2){nc4.y, nc4.y};
        f32x2 ncz = (f32x2){nc4.z, nc4.z};

        // ---- packed distance update + fresh lane max ----
        float nm = -INFINITY;
#pragma unroll
        for (int r = 0; r < 4; ++r) {
            f32x2 dx = px[r] + ncx, dy = py[r] + ncy, dz = pz[r] + ncz;
            f32x2 a = dx * dx, bb = dy * dy, cc = dz * dz;
            f32x2 nd = (a + bb) + cc;
            f32x2 v = __builtin_elementwise_min(dist[r], nd);
            dist[r] = v;
            nm = fmaxf(fmaxf(nm, v.x), v.y);
        }
        lmax = nm;
    }
    __syncthreads();

    for (int s = tid; s < SQ; s += 256) {
        int id = sel[s];
        idx_out[b*SQ + s] = id;
        q_out[(size_t)(b*SQ + s)*3 + 0] = -lnpos[id][0];
        q_out[(size_t)(b*SQ + s)*3 + 1] = -lnpos[id][1];
        q_out[(size_t)(b*SQ + s)*3 + 2] = -lnpos[id][2];
        batch_out[b*SQ + s] = (float)b;
    }
}

// ---------------------------------------------------------------------------
// Kernel 2: radius ball query (unchanged).
// ---------------------------------------------------------------------------
__global__ __launch_bounds__(256)
void ball_kernel(const float* __restrict__ pos, const float* __restrict__ q,
                 int* __restrict__ nbr, int* __restrict__ cnt_out) {
    const int cidx = blockIdx.x;
    const int b = cidx >> 10;
    __shared__ float sd2[CAP];
    __shared__ int   sid[CAP];
    __shared__ int   s_cnt, s_w;
    if (threadIdx.x == 0) { s_cnt = 0; s_w = 0; }
    __syncthreads();

    const float qx = q[(size_t)cidx*3], qy = q[(size_t)cidx*3+1], qz = q[(size_t)cidx*3+2];
    const float* p = pos + (size_t)b * NQ * 3;
    for (int i = threadIdx.x; i < NQ; i += 256) {
        float dx = __fsub_rn(qx, p[3*i]);
        float dy = __fsub_rn(qy, p[3*i+1]);
        float dz = __fsub_rn(qz, p[3*i+2]);
        float d2 = __fadd_rn(__fadd_rn(__fmul_rn(dx, dx), __fmul_rn(dy, dy)),
                             __fmul_rn(dz, dz));
        if (d2 <= R2F) {
            int slot = atomicAdd(&s_cnt, 1);
            if (slot < CAP) { sd2[slot] = d2; sid[slot] = i; }
        }
    }
    __syncthreads();
    int cnt = min(s_cnt, CAP);
    if (cnt <= KQ) {
        for (int t = threadIdx.x; t < cnt; t += 256) nbr[(size_t)cidx*KQ + t] = sid[t];
        if (threadIdx.x == 0) cnt_out[cidx] = cnt;
    } else {
        for (int t = threadIdx.x; t < cnt; t += 256) {
            float d = sd2[t]; int id = sid[t];
            int rank = 0;
            for (int u = 0; u < cnt; ++u) {
                float du = sd2[u];
                rank += (du < d || (du == d && sid[u] < id)) ? 1 : 0;
            }
            if (rank < KQ) { int w = atomicAdd(&s_w, 1); nbr[(size_t)cidx*KQ + w] = id; }
        }
        if (threadIdx.x == 0) cnt_out[cidx] = KQ;
    }
}

// ---------------------------------------------------------------------------
// Kernel 3: conv via bf16 MFMA (unchanged from round 7).
// ---------------------------------------------------------------------------
__global__ __launch_bounds__(256)
void conv_kernel(const float* __restrict__ pos, const float* __restrict__ q,
                 const int* __restrict__ nbr, const int* __restrict__ cnt_in,
                 const float* __restrict__ xw, const float* __restrict__ w1,
                 const u16* __restrict__ w2f, const float* __restrict__ b2,
                 float* __restrict__ out) {
    const int cidx = blockIdx.x;
    const int b = cidx >> 10;
    const int tid = threadIdx.x;
    __shared__ u16  hs[KQ * H1Q];           // 16 KB, swizzled bf16
    __shared__ float dxs[KQ], dys[KQ], dzs[KQ];
    __shared__ int   js[KQ];

    const int cnt = cnt_in[cidx];
    if (cnt == 0) {
        out[(size_t)cidx*COUT + tid] = 0.0f;
        return;
    }
    const float qx = q[(size_t)cidx*3], qy = q[(size_t)cidx*3+1], qz = q[(size_t)cidx*3+2];
    const float* p = pos + (size_t)b * NQ * 3;
    if (tid < cnt) {
        int j = nbr[(size_t)cidx*KQ + tid];
        js[tid]  = j;
        dxs[tid] = p[3*j]   - qx;
        dys[tid] = p[3*j+1] - qy;
        dzs[tid] = p[3*j+2] - qz;
    }
    __syncthreads();

    const float* w1p = w1 + (size_t)CIN * H1Q;   // rows 64..66
    for (int f2 = tid; f2 < KQ*(H1Q/2); f2 += 256) {
        int e = f2 >> 6, hp = (f2 & 63) * 2;
        u32 pack;
        if (e < cnt) {
            int j = js[e];
            const f32x2 xv = *(const f32x2*)(xw + ((size_t)b*NQ + j)*H1Q + hp);
            float dx = dxs[e], dy = dys[e], dz = dzs[e];
            float v0 = xv.x, v1 = xv.y;
            v0 = fmaf(dx, w1p[hp],       v0);
            v0 = fmaf(dy, w1p[H1Q+hp],   v0);
            v0 = fmaf(dz, w1p[2*H1Q+hp], v0);
            v1 = fmaf(dx, w1p[hp+1],       v1);
            v1 = fmaf(dy, w1p[H1Q+hp+1],   v1);
            v1 = fmaf(dz, w1p[2*H1Q+hp+1], v1);
            v0 = fmaxf(v0, 0.0f); v1 = fmaxf(v1, 0.0f);
            pack = (u32)f2bf(v0) | ((u32)f2bf(v1) << 16);
        } else {
            pack = 0u;
        }
        u32 byte = (u32)e*256 + (((u32)hp*2) ^ (((u32)e & 7) << 4));
        *(u32*)((char*)hs + byte) = pack;
    }
    __syncthreads();

    const int w    = tid >> 6;
    const int lane = tid & 63;
    const int row  = lane & 15;
    const int lg   = lane >> 4;

    f32x4v acc[16];
#pragma unroll
    for (int i = 0; i < 16; ++i) acc[i] = (f32x4v){0.f, 0.f, 0.f, 0.f};

#pragma unroll
    for (int kt = 0; kt < 4; ++kt) {
        bf16x8 a[4];
#pragma unroll
        for (int mt = 0; mt < 4; ++mt) {
            u32 byte = (u32)(mt*16 + row)*256
                     + (((u32)(kt*64 + lg*16)) ^ (((u32)row & 7) << 4));
            a[mt] = *(const bf16x8*)((const char*)hs + byte);
        }
#pragma unroll
        for (int ct = 0; ct < 4; ++ct) {
            const int chunk = (w*4 + ct)*4 + kt;
            bf16x8 bf = *(const bf16x8*)(w2f + ((size_t)chunk*64 + lane)*8);
#pragma unroll
            for (int mt = 0; mt < 4; ++mt)
                acc[ct*4 + mt] = __builtin_amdgcn_mfma_f32_16x16x32_bf16(
                    a[mt], bf, acc[ct*4 + mt], 0, 0, 0);
        }
    }

#pragma unroll
    for (int ct = 0; ct < 4; ++ct) {
        float v = -INFINITY;
#pragma unroll
        for (int mt = 0; mt < 4; ++mt) {
#pragma unroll
            for (int r = 0; r < 4; ++r) {
                int rrow = mt*16 + lg*4 + r;
                float av = acc[ct*4 + mt][r];
                v = fmaxf(v, rrow < cnt ? av : -INFINITY);
            }
        }
        v = fmaxf(v, __shfl_xor(v, 16));
        v = fmaxf(v, __shfl_xor(v, 32));
        int n = w*64 + ct*16 + row;
        if (lg == 0) out[(size_t)cidx*COUT + n] = v + b2[n];
    }
}

// ---------------------------------------------------------------------------
extern "C" void kernel_launch(void* const* d_in, const int* in_sizes, int n_in,
                              void* d_out, int out_size, void* d_ws, size_t ws_size,
                              hipStream_t stream) {
    const float* x   = (const float*)d_in[0];
    const float* pos = (const float*)d_in[1];
    const float* w1  = (const float*)d_in[3];
    const float* b1  = (const float*)d_in[4];
    const float* w2  = (const float*)d_in[5];
    const float* b2  = (const float*)d_in[6];

    float* out  = (float*)d_out;                         // [B*S, 256]
    float* qbuf = out + (size_t)BQ*SQ*COUT;              // [B*S, 3]
    float* bbuf = qbuf + (size_t)BQ*SQ*3;                // [B*S]

    char* ws = (char*)d_ws;
    int*   idx = (int*)(ws);                                     // 32 KB
    int*   cnt = (int*)(ws + 32768);                             // 32 KB
    int*   nbr = (int*)(ws + 65536);                             // 2 MB
    float* xw  = (float*)(ws + 65536 + (size_t)BQ*SQ*KQ*4);      // 8 MB
    u16*   w2f = (u16*)(ws + 65536 + (size_t)BQ*SQ*KQ*4
                            + (size_t)BQ*NQ*H1Q*4);              // 64 KB

    const int grid = 8 + XW_BLOCKS + W2C_BLOCKS;
    fps_xw_kernel<<<grid, 256, 0, stream>>>(pos, idx, qbuf, bbuf,
                                            x, w1, b1, xw, w2, w2f);
    ball_kernel  <<<BQ*SQ, 256, 0, stream>>>(pos, qbuf, nbr, cnt);
    conv_kernel  <<<BQ*SQ, 256, 0, stream>>>(pos, qbuf, nbr, cnt, xw, w1,
                                             w2f, b2, out);
}